// Round 1
// baseline (72.948 us; speedup 1.0000x reference)
//
#include <hip/hip_runtime.h>

// Problem constants (from reference): B=32, L=4096, C=21, D=512, K=24, LO=8, M=7, TAO=12
#define LL 4096
#define CC 21
#define TT 64          // t-tile per block
#define XSTR 151       // LDS time stride (>= TT+86=150, odd for bank spread)

// Each lane computes an 8-d x 8-t output tile.
// xrow  = &xs[c*XSTR]  (LDS, circularly staged x column for this channel)
// wtc   = [24][32] weight table: wtc[jk][vo], vo<24 = conv_w[vo][jk], vo>=24 = leftout_w[vo-24][jk]
// EDGE: apply the (wrapped tt < 84) zero mask (only tiles t0 in {0,64,4032})
template<bool EDGE>
__device__ __forceinline__ void compute_item(
    const float* __restrict__ xrow, const float* __restrict__ wtc,
    const float* __restrict__ biasc, float* __restrict__ outp,
    int o0, int d0, int tg, int t0)
{
    float acc[8][8];
    #pragma unroll
    for (int i = 0; i < 8; ++i) {
        float bi = biasc[o0 + i];
        #pragma unroll
        for (int ti = 0; ti < 8; ++ti) acc[ti][i] = bi;
    }
    const int tb = tg * 8 + 85;  // LDS slot of (t = t0+tg*8+ti, k=1) is tb+ti
    #pragma unroll 1
    for (int j = 0; j < 8; ++j) {
        #pragma unroll
        for (int k = 0; k < 3; ++k) {
            const int jk = j * 3 + k;
            float w[8];
            #pragma unroll
            for (int i = 0; i < 8; ++i) w[i] = wtc[jk * 32 + o0 + i];
            #pragma unroll
            for (int ti = 0; ti < 8; ++ti) {
                float v = xrow[tb + (k - 1) - 12 * j + ti];
                if (EDGE) {
                    int delta = t0 + tg * 8 + ti + k - 1;   // unwrapped conv index
                    if ((delta & (LL - 1)) < 84) v = 0.0f;  // mask wrapped tt<84
                }
                #pragma unroll
                for (int i = 0; i < 8; ++i)
                    acc[ti][i] = fmaf(v, w[i], acc[ti][i]);
            }
        }
    }
    #pragma unroll
    for (int ti = 0; ti < 8; ++ti) {
        float* p = outp + (size_t)(tg * 8 + ti) * 512 + d0;
        reinterpret_cast<float4*>(p)[0] =
            make_float4(acc[ti][0], acc[ti][1], acc[ti][2], acc[ti][3]);
        reinterpret_cast<float4*>(p)[1] =
            make_float4(acc[ti][4], acc[ti][5], acc[ti][6], acc[ti][7]);
    }
}

__global__ __launch_bounds__(256) void delay_fir_kernel(
    const float* __restrict__ x,       // [32][4096][21]
    const float* __restrict__ conv_w,  // [24][8][3]
    const float* __restrict__ conv_b,  // [24]
    const float* __restrict__ lw,      // [8][8][3]
    const float* __restrict__ lb,      // [8]
    float* __restrict__ out)           // [32][4096][512]
{
    __shared__ float xs[CC * XSTR];
    __shared__ float wtc[24 * 32];
    __shared__ float biasc[32];

    const int tid = threadIdx.x;
    const int t0 = blockIdx.x * TT;
    const int b  = blockIdx.y;

    // stage weights, transposed to wtc[jk][vo] (vo = virtual output row, 0..31)
    for (int e = tid; e < 24 * 32; e += 256) {
        int jk = e >> 5, vo = e & 31;
        wtc[e] = (vo < 24) ? conv_w[vo * 24 + jk] : lw[(vo - 24) * 24 + jk];
    }
    if (tid < 32) biasc[tid] = (tid < 24) ? conv_b[tid] : lb[tid - 24];

    // stage x circularly: xs[c][s] = x[b][(t0-85+s) & 4095][c], s in [0,150)
    // global reads are contiguous in e = s*21 + c (x is [t][c] layout)
    const float* xb = x + (size_t)b * (LL * CC);
    const int baset = t0 - 85;
    for (int e = tid; e < 150 * CC; e += 256) {
        int s = e / CC, c = e - s * CC;
        int time = (baset + s) & (LL - 1);
        xs[c * XSTR + s] = xb[time * CC + c];
    }
    __syncthreads();

    // lane -> output-channel group: og 0..62 -> (c = og/3, 8 conv outputs),
    // og 63 -> leftout (c=20, weight rows 24..31, d0=504)
    const int og = tid & 63;
    int c, o0, d0;
    if (og == 63) { c = 20; o0 = 24; d0 = 504; }
    else { c = og / 3; int osub = og - c * 3; o0 = osub * 8; d0 = c * 24 + osub * 8; }

    const float* xrow = &xs[c * XSTR];
    float* outp = out + ((size_t)b * LL + t0) * 512;
    const bool edge = (t0 == 0) | (t0 == TT) | (t0 == LL - TT);

    for (int it = 0; it < 2; ++it) {
        int tg = it * 4 + (tid >> 6);   // wave-uniform t-subgroup
        if (edge) compute_item<true >(xrow, wtc, biasc, outp, o0, d0, tg, t0);
        else      compute_item<false>(xrow, wtc, biasc, outp, o0, d0, tg, t0);
    }
}

extern "C" void kernel_launch(void* const* d_in, const int* in_sizes, int n_in,
                              void* d_out, int out_size, void* d_ws, size_t ws_size,
                              hipStream_t stream) {
    const float* x      = (const float*)d_in[0];
    const float* conv_w = (const float*)d_in[1];
    const float* conv_b = (const float*)d_in[2];
    const float* lw     = (const float*)d_in[3];
    const float* lb     = (const float*)d_in[4];
    float* out = (float*)d_out;

    dim3 grid(LL / TT, 32);  // (64 t-tiles, B)
    delay_fir_kernel<<<grid, 256, 0, stream>>>(x, conv_w, conv_b, lw, lb, out);
}